// Round 14
// baseline (111.506 us; speedup 1.0000x reference)
//
#include <hip/hip_runtime.h>

#define N 8192
#define H 256
#define TOPK 16
#define NSEC 11
#define NEG_SLOPE 0.2
#define NB 256                 // K1 blocks (one per CU)
#define NT 256                 // threads per block
#define RPB (N / NB)           // 32 rows per block
#define IDX_SENT 0x7fffffff

__device__ __forceinline__ bool better(double av, int ai, double bv, int bi) {
    return (av > bv) || (av == bv && ai < bi);
}

// ---------------------------------------------------------------------------
// K1: redundant v = W^T a per block (4 independent f64 chains), then s1/s2
// for the block's 32 rows with batched row-loads. R13-proven, unchanged.
// ---------------------------------------------------------------------------
__global__ __launch_bounds__(NT) void compute_v_s(
    const float* __restrict__ E, const float* __restrict__ W,
    const float* __restrict__ a,
    float* __restrict__ s1f, double* __restrict__ s2g)
{
    __shared__ float sa[2 * H];
    __shared__ double sv1[H];
    __shared__ double sv2[H];

    int t = threadIdx.x;
    int blk = blockIdx.x;
    int lane = t & 63;
    int w = t >> 6;  // wave 0..3

    sa[t] = a[t];
    sa[t + H] = a[t + H];
    __syncthreads();

    // ---- phase A: thread t owns column t; 4 independent chains ----
    {
        double a1_0 = 0.0, a1_1 = 0.0, a1_2 = 0.0, a1_3 = 0.0;
        double a2_0 = 0.0, a2_1 = 0.0, a2_2 = 0.0, a2_3 = 0.0;
        for (int j = 0; j < H; j += 4) {
            double w0 = (double)W[(j + 0) * H + t];
            double w1 = (double)W[(j + 1) * H + t];
            double w2 = (double)W[(j + 2) * H + t];
            double w3 = (double)W[(j + 3) * H + t];
            a1_0 += w0 * (double)sa[j + 0];
            a1_1 += w1 * (double)sa[j + 1];
            a1_2 += w2 * (double)sa[j + 2];
            a1_3 += w3 * (double)sa[j + 3];
            a2_0 += w0 * (double)sa[H + j + 0];
            a2_1 += w1 * (double)sa[H + j + 1];
            a2_2 += w2 * (double)sa[H + j + 2];
            a2_3 += w3 * (double)sa[H + j + 3];
        }
        sv1[t] = (a1_0 + a1_1) + (a1_2 + a1_3);
        sv2[t] = (a2_0 + a2_1) + (a2_2 + a2_3);
    }
    __syncthreads();

    // ---- phase B: rows [blk*32 .. +32), wave-per-row, loads batched ----
    {
        float4 e[RPB / 4];
#pragma unroll
        for (int q = 0; q < RPB / 4; ++q) {
            int row = blk * RPB + (w + 4 * q);
            e[q] = ((const float4*)(E + (size_t)row * H))[lane];
        }
        int base = lane * 4;
        double b10 = sv1[base + 0], b11 = sv1[base + 1],
               b12 = sv1[base + 2], b13 = sv1[base + 3];
        double b20 = sv2[base + 0], b21 = sv2[base + 1],
               b22 = sv2[base + 2], b23 = sv2[base + 3];
#pragma unroll
        for (int q = 0; q < RPB / 4; ++q) {
            int row = blk * RPB + (w + 4 * q);
            double acc1 = (double)e[q].x * b10 + (double)e[q].y * b11 +
                          (double)e[q].z * b12 + (double)e[q].w * b13;
            double acc2 = (double)e[q].x * b20 + (double)e[q].y * b21 +
                          (double)e[q].z * b22 + (double)e[q].w * b23;
            for (int o = 32; o > 0; o >>= 1) {
                acc1 += __shfl_down(acc1, o);
                acc2 += __shfl_down(acc2, o);
            }
            if (lane == 0) {
                s1f[row] = (float)acc1;
                s2g[row] = acc2;               // f64 ordering key
            }
        }
    }
}

// ---------------------------------------------------------------------------
// K2: one block per sector, 1024 threads. Thread owns 8 consecutive elements
// -> one latency round for the whole sector. 16 waves each produce a sorted
// 16-list (8 candidate slots/lane in registers — 24 VGPRs, no spill; R11
// pattern). Wave 0 merges 16x16=256 candidates (4/lane, R10/R11-proven
// merge); wave 1 does fill indices; m from per-wave counts.
// ---------------------------------------------------------------------------
__global__ __launch_bounds__(1024) void sector_topk(
    const double* __restrict__ s2g, const int* __restrict__ sec,
    const int* __restrict__ act,
    int* __restrict__ top_idx, int* __restrict__ fill_idx,
    int* __restrict__ m_arr)
{
    __shared__ double wV[16][TOPK];
    __shared__ int wI[16][TOPK];
    __shared__ int wCnt[16];

    int c = blockIdx.x;
    int t = threadIdx.x;   // 0..1023
    int lane = t & 63;
    int w = t >> 6;        // wave 0..15

    // one latency round: 8 consecutive elements per thread
    int j0 = 8 * t;
    int4 aA = *(const int4*)(act + j0);
    int4 aB = *(const int4*)(act + j0 + 4);
    int4 sA = *(const int4*)(sec + j0);
    int4 sB = *(const int4*)(sec + j0 + 4);
    double2 d0 = *(const double2*)(s2g + j0);
    double2 d1 = *(const double2*)(s2g + j0 + 2);
    double2 d2 = *(const double2*)(s2g + j0 + 4);
    double2 d3 = *(const double2*)(s2g + j0 + 6);

    bool p[8];
    p[0] = (aA.x != 0) && (sA.x == c);
    p[1] = (aA.y != 0) && (sA.y == c);
    p[2] = (aA.z != 0) && (sA.z == c);
    p[3] = (aA.w != 0) && (sA.w == c);
    p[4] = (aB.x != 0) && (sB.x == c);
    p[5] = (aB.y != 0) && (sB.y == c);
    p[6] = (aB.z != 0) && (sB.z == c);
    p[7] = (aB.w != 0) && (sB.w == c);

    double v[8];
    int ix[8];
    v[0] = p[0] ? d0.x : -INFINITY;  ix[0] = p[0] ? (j0 + 0) : IDX_SENT;
    v[1] = p[1] ? d0.y : -INFINITY;  ix[1] = p[1] ? (j0 + 1) : IDX_SENT;
    v[2] = p[2] ? d1.x : -INFINITY;  ix[2] = p[2] ? (j0 + 2) : IDX_SENT;
    v[3] = p[3] ? d1.y : -INFINITY;  ix[3] = p[3] ? (j0 + 3) : IDX_SENT;
    v[4] = p[4] ? d2.x : -INFINITY;  ix[4] = p[4] ? (j0 + 4) : IDX_SENT;
    v[5] = p[5] ? d2.y : -INFINITY;  ix[5] = p[5] ? (j0 + 5) : IDX_SENT;
    v[6] = p[6] ? d3.x : -INFINITY;  ix[6] = p[6] ? (j0 + 6) : IDX_SENT;
    v[7] = p[7] ? d3.y : -INFINITY;  ix[7] = p[7] ? (j0 + 7) : IDX_SENT;

    int cnt = 0;
#pragma unroll
    for (int k = 0; k < 8; ++k) cnt += __popcll(__ballot(p[k]));

    // per-wave top-16 of this wave's 512 elements
    for (int r = 0; r < TOPK; ++r) {
        double bv = v[0];
        int bi = ix[0];
#pragma unroll
        for (int q = 1; q < 8; ++q)
            if (better(v[q], ix[q], bv, bi)) { bv = v[q]; bi = ix[q]; }
        for (int o = 32; o > 0; o >>= 1) {
            double ov = __shfl_xor(bv, o);
            int oi = __shfl_xor(bi, o);
            if (better(ov, oi, bv, bi)) { bv = ov; bi = oi; }
        }
#pragma unroll
        for (int q = 0; q < 8; ++q)
            if (ix[q] == bi) { v[q] = -INFINITY; ix[q] = IDX_SENT; }
        if (lane == 0) {
            wV[w][r] = bv;
            wI[w][r] = bi;
        }
    }
    if (lane == 0) wCnt[w] = cnt;
    __syncthreads();

    if (w == 0) {
        // merge 16 sorted 16-lists = 256 candidates, 4 per lane
        const double* fV = &wV[0][0];
        const int* fI = &wI[0][0];
        double mv[4];
        int mi[4];
#pragma unroll
        for (int q = 0; q < 4; ++q) {
            mv[q] = fV[q * 64 + lane];
            mi[q] = fI[q * 64 + lane];
        }
        for (int r = 0; r < TOPK; ++r) {
            double bv = mv[0];
            int bi = mi[0];
#pragma unroll
            for (int q = 1; q < 4; ++q)
                if (better(mv[q], mi[q], bv, bi)) { bv = mv[q]; bi = mi[q]; }
            for (int o = 32; o > 0; o >>= 1) {
                double ov = __shfl_xor(bv, o);
                int oi = __shfl_xor(bi, o);
                if (better(ov, oi, bv, bi)) { bv = ov; bi = oi; }
            }
#pragma unroll
            for (int q = 0; q < 4; ++q)
                if (mi[q] == bi) { mv[q] = -INFINITY; mi[q] = IDX_SENT; }
            if (lane == 0) top_idx[c * TOPK + r] = (bi == IDX_SENT) ? -1 : bi;
        }
        // m = min(16, total active in sector)
        int cl = (lane < 16) ? wCnt[lane] : 0;
        for (int o = 32; o > 0; o >>= 1) cl += __shfl_xor(cl, o);
        if (lane == 0) m_arr[c] = (cl < TOPK) ? cl : TOPK;
    }

    if (w == 1) {
        // fill indices: first 16 j failing the predicate (L2-hot act/sec)
        int cnt2 = 0;
        for (int basej = 0; basej < N && cnt2 < TOPK; basej += 64) {
            int j = basej + lane;
            bool fail = !((act[j] != 0) && (sec[j] == c));
            unsigned long long mask = __ballot(fail);
            if (fail) {
                int rank = cnt2 + __popcll(mask & ((1ull << lane) - 1));
                if (rank < TOPK) fill_idx[c * TOPK + rank] = j;
            }
            cnt2 += __popcll(mask);
        }
    }
}

// ---------------------------------------------------------------------------
// K3: write outputs (weight, index-as-float, valid-as-float planes).
// R11/R13-proven, unchanged.
// ---------------------------------------------------------------------------
__global__ __launch_bounds__(NT) void write_out(const float* __restrict__ s1f,
                                                const double* __restrict__ s2g,
                                                const int* __restrict__ sec,
                                                const int* __restrict__ act,
                                                const int* __restrict__ top_idx,
                                                const int* __restrict__ fill_idx,
                                                const int* __restrict__ m_arr,
                                                float* __restrict__ out) {
    int gid = blockIdx.x * NT + threadIdx.x;  // N*TOPK total
    int i = gid >> 4;
    int slot = gid & 15;

    float wgt = 0.0f;
    float fidx;
    float fvalid = 0.0f;

    if (act[i] == 0) {
        fidx = (float)slot;  // all -inf row: stable top_k -> indices 0..15
    } else {
        int c = sec[i];
        int m = m_arr[c];
        if (slot < m) {
            int j = top_idx[c * TOPK + slot];
            double x = (double)s1f[i] + s2g[j];
            double attv = (x >= 0.0) ? x : NEG_SLOPE * x;
            wgt = (float)attv;
            fvalid = 1.0f;
            fidx = (float)j;
        } else {
            fidx = (float)fill_idx[c * TOPK + (slot - m)];
        }
    }

    out[gid] = wgt;
    out[N * TOPK + gid] = fidx;
    out[2 * N * TOPK + gid] = fvalid;
}

extern "C" void kernel_launch(void* const* d_in, const int* in_sizes, int n_in,
                              void* d_out, int out_size, void* d_ws, size_t ws_size,
                              hipStream_t stream) {
    const float* E = (const float*)d_in[0];
    const float* W = (const float*)d_in[1];
    const float* a = (const float*)d_in[2];
    const int* sec = (const int*)d_in[3];
    const int* act = (const int*)d_in[4];  // bool input uploaded as int32

    // workspace (~99 KB, 8-byte aligned first) — within proven range
    char* ws = (char*)d_ws;
    double* s2g = (double*)ws;                 // N f64
    float* s1f = (float*)(s2g + N);            // N f32
    int* top_idx = (int*)(s1f + N);            // NSEC*TOPK
    int* fill_idx = top_idx + NSEC * TOPK;     // NSEC*TOPK
    int* m_arr = fill_idx + NSEC * TOPK;       // NSEC

    float* out = (float*)d_out;

    hipLaunchKernelGGL(compute_v_s, dim3(NB), dim3(NT), 0, stream,
                       E, W, a, s1f, s2g);
    hipLaunchKernelGGL(sector_topk, dim3(NSEC), dim3(1024), 0, stream,
                       s2g, sec, act, top_idx, fill_idx, m_arr);
    hipLaunchKernelGGL(write_out, dim3((N * TOPK) / NT), dim3(NT), 0, stream,
                       s1f, s2g, sec, act, top_idx, fill_idx, m_arr, out);
}